// Round 10
// baseline (123.263 us; speedup 1.0000x reference)
//
#include <hip/hip_runtime.h>
#include <hip/hip_bf16.h>
#include <stdint.h>

// ============================================================================
// ImageManifoldHead on MI355X (gfx950) — round 10
//
// Pipeline:
//   prep:   W_patch -> WpT bf16 [512][768]; W_out -> WoT bf16 [512][512]
//           manifold_prep: Wcsg bf16[16][512]
//   gemm1_fused: patchify + GEMM in one (v5 skeleton, reg-staged A from
//                images f32 with on-the-fly bf16 cvt, gload_lds B) -> x bf16
//   manifold_v5: coords/K0 (MFMA) + embed/LN (VALU) fused, 1 wave/16 rows,
//                in-place on x
//   gemm2:  x @ WoT^T + b_out -> out f32   (v5 structure)
//
// R9->R10: deleted patchify (77 MB Apat round trip) and the Cbuf round trip.
// ============================================================================

typedef __bf16 bf16_t;
typedef bf16_t bf16x8 __attribute__((ext_vector_type(8)));
typedef bf16_t bf16x4 __attribute__((ext_vector_type(4)));
typedef float  f32x4  __attribute__((ext_vector_type(4)));

#define IMG     448
#define PSZ     16
#define NHP     28
#define NPATCH  784
#define PDIM    768
#define DMODEL  512
#define MROWS   25088

__device__ __forceinline__ void gload16(void* lds, const void* g) {
  __builtin_amdgcn_global_load_lds(
      (__attribute__((address_space(1))) void*)(uintptr_t)g,
      (__attribute__((address_space(3))) void*)lds,
      16, 0, 0);
}

// ---------------------------------------------------------------------------
// prep: transpose f32 [K][N] -> bf16 [N][K]
// ---------------------------------------------------------------------------
__global__ __launch_bounds__(256) void transpose_to_bf16(
    const float* __restrict__ src, bf16_t* __restrict__ dst, int K, int N)
{
  __shared__ float t[64][65];
  const int tx = threadIdx.x;
  const int ty = threadIdx.y;
  const int bx = blockIdx.x * 64;
  const int by = blockIdx.y * 64;
  #pragma unroll
  for (int r = ty; r < 64; r += 4)
    t[r][tx] = src[(size_t)(by + r) * N + (bx + tx)];
  __syncthreads();
  #pragma unroll
  for (int r = ty; r < 64; r += 4)
    dst[(size_t)(bx + r) * K + (by + tx)] = (bf16_t)t[tx][r];
}

// ---------------------------------------------------------------------------
// manifold_prep: Wcsg [16][512]: r<8: Wc[n][r]; r 8-11: Ws[n][r-8]; else 0
// ---------------------------------------------------------------------------
__global__ __launch_bounds__(256) void manifold_prep(
    const float* __restrict__ Wc, const float* __restrict__ Ws,
    bf16_t* __restrict__ Wcsg)
{
  const int idx = blockIdx.x * 256 + threadIdx.x;   // grid 32 -> 8192
  if (idx < 8192) {
    const int r = idx >> 9, n = idx & 511;
    float v = 0.f;
    if (r < 8)       v = Wc[n * 8 + r];
    else if (r < 12) v = Ws[n * 4 + (r - 8)];
    Wcsg[idx] = (bf16_t)v;
  }
}

// ---------------------------------------------------------------------------
// gemm1_fused: x = patchify(images) @ WpT^T + b_patch + pos_embed  (bf16 out)
// v5 skeleton: BM=64, BN=128, BK=64, 4 waves, grid 1568, XCD swizzle.
// A staged from images: thread (row=tid>>2, seg=tid&3) loads one 16-f32
// segment (images[b,c,ph*16+i0+seg, pw*16..+16]), cvt, 2 swizzled ds_writes.
// B staged via global_load_lds (pre-swizzled source).
// ---------------------------------------------------------------------------
__global__ __launch_bounds__(256) void gemm1_fused(
    const float* __restrict__ images, const bf16_t* __restrict__ BT,
    const float* __restrict__ bias, const float* __restrict__ pos,
    bf16_t* __restrict__ outp)
{
  __shared__ bf16_t As[64 * 64];    //  8 KB
  __shared__ bf16_t Bs[128 * 64];   // 16 KB
  constexpr int NT = PDIM / 64;     // 12

  const int tid  = threadIdx.x;
  const int orig = blockIdx.x;
  const int wg   = (orig & 7) * 196 + (orig >> 3);   // bijective, 1568=8*196
  const int n0   = (wg & 3) * 128;
  const int m0   = (wg >> 2) * 64;

  const int wave = tid >> 6, lane = tid & 63;

  // ---- A staging mapping (patchify gather) ----
  const int r_loc = tid >> 2;        // 0..63
  const int seg   = tid & 3;         // i - i0
  {
  }
  const int m  = m0 + r_loc;
  const int b  = m / NPATCH;
  const int p  = m - b * NPATCH;
  const int ph = p / NHP;
  const int pw = p - ph * NHP;
  const float* abase = images + ((size_t)(b * 3) * IMG + ph * PSZ) * IMG + pw * PSZ;
  bf16_t* aw0 = As + r_loc * 64 + (((2 * seg)     ^ (r_loc & 7)) * 8);
  bf16_t* aw1 = As + r_loc * 64 + (((2 * seg + 1) ^ (r_loc & 7)) * 8);

  // ---- B staging (gload_lds, pre-swizzled source) ----
  const int ra = lane >> 3;
  const int ca = (lane & 7) ^ ra;
  const bf16_t* bg = BT + (size_t)(n0 + wave * 8 + ra) * PDIM + ca * 8;
  bf16_t* bl0 = Bs + (wave * 8) * 64;
  bf16_t* bl1 = Bs + (wave * 8 + 32) * 64;
  bf16_t* bl2 = Bs + (wave * 8 + 64) * 64;
  bf16_t* bl3 = Bs + (wave * 8 + 96) * 64;

  const int wm = (wave >> 1) * 32;
  const int wn = (wave & 1) * 64;
  const int lr = lane & 15;
  const int lt = lane >> 4;

  f32x4 acc[2][4] = {};

  for (int t = 0; t < NT; ++t) {
    const int k0 = t * 64;
    // issue image loads early — only address-dependent, fly across barrier
    const float* asrc = abase + (size_t)(t >> 2) * (IMG * IMG)
                              + ((t & 3) * 4 + seg) * IMG;
    const float4 v0 = *(const float4*)(asrc + 0);
    const float4 v1 = *(const float4*)(asrc + 4);
    const float4 v2 = *(const float4*)(asrc + 8);
    const float4 v3 = *(const float4*)(asrc + 12);

    __syncthreads();                 // prev step's LDS reads complete
    bf16x8 w0, w1;
    w0[0] = (bf16_t)v0.x; w0[1] = (bf16_t)v0.y; w0[2] = (bf16_t)v0.z; w0[3] = (bf16_t)v0.w;
    w0[4] = (bf16_t)v1.x; w0[5] = (bf16_t)v1.y; w0[6] = (bf16_t)v1.z; w0[7] = (bf16_t)v1.w;
    w1[0] = (bf16_t)v2.x; w1[1] = (bf16_t)v2.y; w1[2] = (bf16_t)v2.z; w1[3] = (bf16_t)v2.w;
    w1[4] = (bf16_t)v3.x; w1[5] = (bf16_t)v3.y; w1[6] = (bf16_t)v3.z; w1[7] = (bf16_t)v3.w;
    *(bf16x8*)aw0 = w0;
    *(bf16x8*)aw1 = w1;
    gload16(bl0, bg + k0);
    gload16(bl1, bg + 32 * PDIM + k0);
    gload16(bl2, bg + 64 * PDIM + k0);
    gload16(bl3, bg + 96 * PDIM + k0);
    __syncthreads();                 // drains ds_writes + DMA

    #pragma unroll
    for (int ks = 0; ks < 2; ++ks) {
      const int c = ks * 4 + lt;
      bf16x8 af[2], bfr[4];
      #pragma unroll
      for (int i = 0; i < 2; ++i) {
        const int row = wm + i * 16 + lr;
        af[i] = *(const bf16x8*)&As[row * 64 + ((c ^ (row & 7)) * 8)];
      }
      #pragma unroll
      for (int j = 0; j < 4; ++j) {
        const int row = wn + j * 16 + lr;
        bfr[j] = *(const bf16x8*)&Bs[row * 64 + ((c ^ (row & 7)) * 8)];
      }
      #pragma unroll
      for (int i = 0; i < 2; ++i)
        #pragma unroll
        for (int j = 0; j < 4; ++j)
          acc[i][j] = __builtin_amdgcn_mfma_f32_16x16x32_bf16(af[i], bfr[j], acc[i][j], 0, 0, 0);
    }
  }

  // epilogue: + b_patch + pos_embed
  const int q4 = lt << 2;
  const int colb = n0 + wn;
  #pragma unroll
  for (int i = 0; i < 2; ++i) {
    #pragma unroll
    for (int r = 0; r < 4; ++r) {
      const int mm = m0 + wm + i * 16 + q4 + r;
      const int pp = mm % NPATCH;
      const float* pe = pos + (size_t)pp * DMODEL;
      bf16_t* orow = outp + (size_t)mm * DMODEL;
      #pragma unroll
      for (int j = 0; j < 4; ++j) {
        const int nn = colb + j * 16 + lr;
        orow[nn] = (bf16_t)(acc[i][j][r] + bias[nn] + pe[nn]);
      }
    }
  }
}

// ---------------------------------------------------------------------------
// gemm v5 (for gemm2): C[M][512] = A[M][512] @ BT[512][512]^T + b_out (f32)
// ---------------------------------------------------------------------------
__global__ __launch_bounds__(256) void gemm2_v5(
    const bf16_t* __restrict__ A, const bf16_t* __restrict__ BT,
    const float* __restrict__ bias, float* __restrict__ outp)
{
  __shared__ bf16_t As[64 * 64];
  __shared__ bf16_t Bs[128 * 64];
  constexpr int KDIM = DMODEL;
  constexpr int NT = KDIM / 64;

  const int tid  = threadIdx.x;
  const int orig = blockIdx.x;
  const int wg   = (orig & 7) * 196 + (orig >> 3);
  const int n0   = (wg & 3) * 128;
  const int m0   = (wg >> 2) * 64;

  const int wave = tid >> 6, lane = tid & 63;
  const int ra = lane >> 3;
  const int ca = (lane & 7) ^ ra;
  const bf16_t* ag = A  + (size_t)(m0 + wave * 8 + ra) * KDIM + ca * 8;
  const bf16_t* bg = BT + (size_t)(n0 + wave * 8 + ra) * KDIM + ca * 8;
  bf16_t* al0 = As + (wave * 8) * 64;
  bf16_t* al1 = As + (wave * 8 + 32) * 64;
  bf16_t* bl0 = Bs + (wave * 8) * 64;
  bf16_t* bl1 = Bs + (wave * 8 + 32) * 64;
  bf16_t* bl2 = Bs + (wave * 8 + 64) * 64;
  bf16_t* bl3 = Bs + (wave * 8 + 96) * 64;

  const int wm = (wave >> 1) * 32;
  const int wn = (wave & 1) * 64;
  const int lr = lane & 15;
  const int lt = lane >> 4;

  f32x4 acc[2][4] = {};

  for (int t = 0; t < NT; ++t) {
    const int k0 = t * 64;
    __syncthreads();
    gload16(al0, ag + k0);
    gload16(al1, ag + 32 * KDIM + k0);
    gload16(bl0, bg + k0);
    gload16(bl1, bg + 32 * KDIM + k0);
    gload16(bl2, bg + 64 * KDIM + k0);
    gload16(bl3, bg + 96 * KDIM + k0);
    __syncthreads();

    #pragma unroll
    for (int ks = 0; ks < 2; ++ks) {
      const int c = ks * 4 + lt;
      bf16x8 af[2], bfr[4];
      #pragma unroll
      for (int i = 0; i < 2; ++i) {
        const int row = wm + i * 16 + lr;
        af[i] = *(const bf16x8*)&As[row * 64 + ((c ^ (row & 7)) * 8)];
      }
      #pragma unroll
      for (int j = 0; j < 4; ++j) {
        const int row = wn + j * 16 + lr;
        bfr[j] = *(const bf16x8*)&Bs[row * 64 + ((c ^ (row & 7)) * 8)];
      }
      #pragma unroll
      for (int i = 0; i < 2; ++i)
        #pragma unroll
        for (int j = 0; j < 4; ++j)
          acc[i][j] = __builtin_amdgcn_mfma_f32_16x16x32_bf16(af[i], bfr[j], acc[i][j], 0, 0, 0);
    }
  }

  const int q4 = lt << 2;
  const int colb = n0 + wn;
  #pragma unroll
  for (int i = 0; i < 2; ++i) {
    #pragma unroll
    for (int r = 0; r < 4; ++r) {
      const int mm = m0 + wm + i * 16 + q4 + r;
      float* orow = outp + (size_t)mm * DMODEL;
      #pragma unroll
      for (int j = 0; j < 4; ++j) {
        const int nn = colb + j * 16 + lr;
        orow[nn] = acc[i][j][r] + bias[nn];
      }
    }
  }
}

// ---------------------------------------------------------------------------
// manifold_v5: coords/K0 (MFMA) + embed/residual/LN (VALU), fused, in-place.
// 1 wave per 16 rows, grid = MROWS/16 = 1568, no inter-wave sync.
// Phase A (proven K1): D1 = mfma(A=Wcs, B=x rows); lane (q4,lr) holds comps
//   q4+r of row lr. coords -> cbuf[16][12] LDS; K0 -> cbuf[.][8].
// Phase B (proven K2 layout): lane owns cols n=lane*8..+8 for all 16 rows;
//   We/be/gamma/beta in regs (f32); x re-read from L1; LN butterfly; store.
// ---------------------------------------------------------------------------
__global__ __launch_bounds__(64) void manifold_v5(
    bf16_t* __restrict__ x, const bf16_t* __restrict__ Wcsg,
    const float* __restrict__ b_coord, const float* __restrict__ b_spinor,
    const float* __restrict__ We, const float* __restrict__ be,
    const float* __restrict__ gamma, const float* __restrict__ beta)
{
  __shared__ float cbuf[16][12];   // c0..7, K0 at [8]; stride 12 keeps 16B align

  const int lane = threadIdx.x;
  const int lr   = lane & 15;
  const int lk   = (lane >> 4) << 3;    // 0,8,16,24
  const int q4   = (lane >> 4) << 2;    // 0,4,8,12
  const int m0w  = blockIdx.x * 16;

  float bbv[4];
  #pragma unroll
  for (int r = 0; r < 4; ++r) {
    if (q4 == 0)      bbv[r] = b_coord[r];
    else if (q4 == 4) bbv[r] = b_coord[4 + r];
    else if (q4 == 8) bbv[r] = b_spinor[r];
    else              bbv[r] = 0.f;
  }

  // ---- phase A: coords + K0 ----
  const bf16_t* xrow = x + (size_t)(m0w + lr) * DMODEL + lk;
  const bf16_t* wrow = Wcsg + lr * DMODEL + lk;
  f32x4 acc1 = {0.f, 0.f, 0.f, 0.f};
  #pragma unroll
  for (int ks = 0; ks < 16; ++ks) {
    const bf16x8 bf = *(const bf16x8*)(xrow + ks * 32);
    const bf16x8 wf = *(const bf16x8*)(wrow + ks * 32);
    acc1 = __builtin_amdgcn_mfma_f32_16x16x32_bf16(wf, bf, acc1, 0, 0, 0);
  }
  float sv[4];
  #pragma unroll
  for (int r = 0; r < 4; ++r) sv[r] = acc1[r] + bbv[r];

  if (q4 == 8) {
    cbuf[lr][8] = sv[0] * sv[0] + sv[1] * sv[1] + sv[2] * sv[2] + sv[3] * sv[3];
  } else if (q4 == 0 || q4 == 4) {
    f32x4 st = {sv[0], sv[1], sv[2], sv[3]};
    *(f32x4*)&cbuf[lr][q4] = st;
  }
  __syncthreads();   // single wave: cheap; orders cbuf writes vs reads

  // ---- phase B: embed + residual + LN ----
  const int n0 = lane * 8;
  f32x4 wlo[8], whi[8];
  #pragma unroll
  for (int dc = 0; dc < 8; ++dc) {
    wlo[dc] = *(const f32x4*)&We[dc * DMODEL + n0];
    whi[dc] = *(const f32x4*)&We[dc * DMODEL + n0 + 4];
  }
  const f32x4 beL = *(const f32x4*)&be[n0];
  const f32x4 beH = *(const f32x4*)&be[n0 + 4];
  const f32x4 gL  = *(const f32x4*)&gamma[n0];
  const f32x4 gH  = *(const f32x4*)&gamma[n0 + 4];
  const f32x4 btL = *(const f32x4*)&beta[n0];
  const f32x4 btH = *(const f32x4*)&beta[n0 + 4];

  #pragma unroll 2
  for (int rr = 0; rr < 16; ++rr) {
    const size_t row = (size_t)m0w + rr;
    const bf16x8 xv = *(const bf16x8*)(x + row * DMODEL + n0);
    const f32x4 c0 = *(const f32x4*)&cbuf[rr][0];
    const f32x4 c1 = *(const f32x4*)&cbuf[rr][4];
    const float k0 = cbuf[rr][8];

    float v[8];
    float s1 = 0.f, s2 = 0.f;
    #pragma unroll
    for (int e = 0; e < 4; ++e) {
      float xm = beL[e];
      #pragma unroll
      for (int dc = 0; dc < 4; ++dc) xm += c0[dc] * wlo[dc][e];
      #pragma unroll
      for (int dc = 0; dc < 4; ++dc) xm += c1[dc] * wlo[4 + dc][e];
      const float vv = xm * k0 + (float)xv[e];
      v[e] = vv; s1 += vv; s2 += vv * vv;
    }
    #pragma unroll
    for (int e = 0; e < 4; ++e) {
      float xm = beH[e];
      #pragma unroll
      for (int dc = 0; dc < 4; ++dc) xm += c0[dc] * whi[dc][e];
      #pragma unroll
      for (int dc = 0; dc < 4; ++dc) xm += c1[dc] * whi[4 + dc][e];
      const float vv = xm * k0 + (float)xv[4 + e];
      v[4 + e] = vv; s1 += vv; s2 += vv * vv;
    }

    #pragma unroll
    for (int off = 1; off <= 32; off <<= 1) {
      s1 += __shfl_xor(s1, off, 64);
      s2 += __shfl_xor(s2, off, 64);
    }
    const float mu  = s1 * (1.f / 512.f);
    const float var = s2 * (1.f / 512.f) - mu * mu;
    const float rs  = rsqrtf(var + 1e-5f);

    bf16x8 o;
    #pragma unroll
    for (int e = 0; e < 4; ++e) {
      o[e]     = (bf16_t)((v[e]     - mu) * rs * gL[e] + btL[e]);
      o[4 + e] = (bf16_t)((v[4 + e] - mu) * rs * gH[e] + btH[e]);
    }
    *(bf16x8*)(x + row * DMODEL + n0) = o;
  }
}

// ---------------------------------------------------------------------------
extern "C" void kernel_launch(void* const* d_in, const int* in_sizes, int n_in,
                              void* d_out, int out_size, void* d_ws, size_t ws_size,
                              hipStream_t stream)
{
  const float* images    = (const float*)d_in[0];
  const float* W_patch   = (const float*)d_in[1];
  const float* b_patch   = (const float*)d_in[2];
  const float* pos_embed = (const float*)d_in[3];
  const float* W_coord   = (const float*)d_in[4];
  const float* b_coord   = (const float*)d_in[5];
  const float* W_spinor  = (const float*)d_in[6];
  const float* b_spinor  = (const float*)d_in[7];
  const float* W_embed   = (const float*)d_in[8];
  const float* b_embed   = (const float*)d_in[9];
  const float* ln_gamma  = (const float*)d_in[10];
  const float* ln_beta   = (const float*)d_in[11];
  const float* W_out     = (const float*)d_in[12];
  const float* b_out     = (const float*)d_in[13];
  float* out = (float*)d_out;

  const size_t SZ_X    = (size_t)MROWS * DMODEL * 2;   // 25,690,112
  const size_t SZ_WPT  = (size_t)DMODEL * PDIM * 2;    //    786,432
  const size_t SZ_WOT  = (size_t)DMODEL * DMODEL * 2;  //    524,288

  char* ws = (char*)d_ws;
  char* p  = ws;
  bf16_t* x    = (bf16_t*)p;   p += SZ_X;
  bf16_t* WpT  = (bf16_t*)p;   p += SZ_WPT;
  bf16_t* WoT  = (bf16_t*)p;   p += SZ_WOT;
  bf16_t* Wcsg = (bf16_t*)p;

  hipLaunchKernelGGL(transpose_to_bf16, dim3(8, 12), dim3(64, 4), 0, stream,
                     W_patch, WpT, PDIM, DMODEL);
  hipLaunchKernelGGL(transpose_to_bf16, dim3(8, 8), dim3(64, 4), 0, stream,
                     W_out, WoT, DMODEL, DMODEL);
  hipLaunchKernelGGL(manifold_prep, dim3(32), dim3(256), 0, stream,
                     W_coord, W_spinor, Wcsg);

  hipLaunchKernelGGL(gemm1_fused, dim3(1568), dim3(256), 0, stream,
                     images, WpT, b_patch, pos_embed, x);

  hipLaunchKernelGGL(manifold_v5, dim3(MROWS / 16), dim3(64), 0, stream,
                     x, Wcsg, b_coord, b_spinor, W_embed, b_embed, ln_gamma, ln_beta);

  hipLaunchKernelGGL(gemm2_v5, dim3(1568), dim3(256), 0, stream,
                     x, WoT, b_out, out);
}

// Round 11
// 118.457 us; speedup vs baseline: 1.0406x; 1.0406x over previous
//
#include <hip/hip_runtime.h>
#include <hip/hip_bf16.h>
#include <stdint.h>

// ============================================================================
// ImageManifoldHead on MI355X (gfx950) — round 11
//
// Pipeline:
//   prep:   W_patch -> WpT bf16 [512][768]; W_out -> WoT bf16 [512][512]
//           manifold_prep: Wcsg bf16[16][512]
//   patchify_bf16: images f32 -> Apat bf16 [25088][768]   (BW-bound pass)
//   gemm1:  Apat @ WpT^T + b_patch + pos -> x bf16   (pipelined v6)
//   manifold_v5: coords/K0 (MFMA) + embed/LN (VALU), 1 wave/16 rows, in-place
//   gemm2:  x @ WoT^T + b_out -> out f32             (pipelined v6)
//
// gemm v6 = v5 tile (BM=64,BN=128,BK=64, 4 waves, chunk-XOR swizzle) +
// counted-vmcnt 3-buffer pipeline (T4): one RAW s_barrier per K-step,
// vmcnt(6) never 0 in steady state, STAGE(t+2) lands 2 iterations later.
// R10 lesson: patchify-in-GEMM quadruples image traffic — keep it separate.
// ============================================================================

typedef __bf16 bf16_t;
typedef bf16_t bf16x8 __attribute__((ext_vector_type(8)));
typedef bf16_t bf16x4 __attribute__((ext_vector_type(4)));
typedef float  f32x4  __attribute__((ext_vector_type(4)));

#define IMG     448
#define PSZ     16
#define NHP     28
#define NPATCH  784
#define PDIM    768
#define DMODEL  512
#define MROWS   25088

__device__ __forceinline__ void gload16(void* lds, const void* g) {
  __builtin_amdgcn_global_load_lds(
      (__attribute__((address_space(1))) void*)(uintptr_t)g,
      (__attribute__((address_space(3))) void*)lds,
      16, 0, 0);
}

// ---------------------------------------------------------------------------
// prep: transpose f32 [K][N] -> bf16 [N][K]
// ---------------------------------------------------------------------------
__global__ __launch_bounds__(256) void transpose_to_bf16(
    const float* __restrict__ src, bf16_t* __restrict__ dst, int K, int N)
{
  __shared__ float t[64][65];
  const int tx = threadIdx.x;
  const int ty = threadIdx.y;
  const int bx = blockIdx.x * 64;
  const int by = blockIdx.y * 64;
  #pragma unroll
  for (int r = ty; r < 64; r += 4)
    t[r][tx] = src[(size_t)(by + r) * N + (bx + tx)];
  __syncthreads();
  #pragma unroll
  for (int r = ty; r < 64; r += 4)
    dst[(size_t)(bx + r) * K + (by + tx)] = (bf16_t)t[tx][r];
}

// ---------------------------------------------------------------------------
// manifold_prep: Wcsg [16][512]: r<8: Wc[n][r]; r 8-11: Ws[n][r-8]; else 0
// ---------------------------------------------------------------------------
__global__ __launch_bounds__(256) void manifold_prep(
    const float* __restrict__ Wc, const float* __restrict__ Ws,
    bf16_t* __restrict__ Wcsg)
{
  const int idx = blockIdx.x * 256 + threadIdx.x;   // grid 32 -> 8192
  if (idx < 8192) {
    const int r = idx >> 9, n = idx & 511;
    float v = 0.f;
    if (r < 8)       v = Wc[n * 8 + r];
    else if (r < 12) v = Ws[n * 4 + (r - 8)];
    Wcsg[idx] = (bf16_t)v;
  }
}

// ---------------------------------------------------------------------------
// patchify_bf16: images (B,3,448,448) f32 -> Apat [25088][768] bf16
// ---------------------------------------------------------------------------
__global__ __launch_bounds__(256) void patchify_bf16(
    const float* __restrict__ images, bf16_t* __restrict__ Apat)
{
  __shared__ bf16_t t[16][456];
  const int tid = threadIdx.x;
  const int bid = blockIdx.x;
  const int b = bid / 84, rem = bid % 84;
  const int c = rem / 28, ph = rem % 28;
  const float* src = images + ((size_t)(b * 3 + c) * IMG + ph * PSZ) * IMG;

  #pragma unroll
  for (int idx = tid; idx < 16 * 112; idx += 256) {
    const int i = idx / 112, x4 = idx % 112;
    const float4 v = *(const float4*)(src + (size_t)i * IMG + x4 * 4);
    bf16x4 w;
    w[0] = (bf16_t)v.x; w[1] = (bf16_t)v.y; w[2] = (bf16_t)v.z; w[3] = (bf16_t)v.w;
    *(bf16x4*)&t[i][x4 * 4] = w;
  }
  __syncthreads();

  const size_t mbase = (size_t)b * NPATCH + (size_t)ph * NHP;
  #pragma unroll
  for (int idx = tid; idx < 28 * 64; idx += 256) {
    const int pw = idx >> 6, e = idx & 63;
    const int i = e >> 2, j4 = e & 3;
    const bf16x4 w = *(const bf16x4*)&t[i][pw * 16 + j4 * 4];
    *(bf16x4*)&Apat[(mbase + pw) * PDIM + c * 256 + i * 16 + j4 * 4] = w;
  }
}

// ---------------------------------------------------------------------------
// gemm v6 (counted-vmcnt 3-buffer pipeline):
//   C[M][512] = A[M][KDIM] @ BT[512][KDIM]^T
// BM=64, BN=128, BK=64, 4 waves; grid 1568, XCD swizzle; chunk-XOR LDS swz.
// Per iter: vmcnt(6) -> s_barrier -> STAGE(t+2) -> ds_read(t) + 16 MFMA.
// ---------------------------------------------------------------------------
template<int KDIM, int EPI>
__global__ __launch_bounds__(256) void gemm_bf16(
    const bf16_t* __restrict__ A, const bf16_t* __restrict__ BT,
    const float* __restrict__ bias, const float* __restrict__ pos,
    void* __restrict__ outp)
{
  __shared__ bf16_t As[3 * 64 * 64];    // 24 KB
  __shared__ bf16_t Bs[3 * 128 * 64];   // 48 KB
  constexpr int ABUF = 64 * 64;
  constexpr int BBUF = 128 * 64;
  constexpr int NT = KDIM / 64;

  const int tid  = threadIdx.x;
  const int orig = blockIdx.x;
  const int wg   = (orig & 7) * 196 + (orig >> 3);   // bijective, 1568=8*196
  const int n0   = (wg & 3) * 128;
  const int m0   = (wg >> 2) * 64;

  const int wave = tid >> 6, lane = tid & 63;

  // staging: lane -> (row ra 0..7, global chunk ca = (lane&7) ^ ra)
  const int ra = lane >> 3;
  const int ca = (lane & 7) ^ ra;
  const bf16_t* ag = A  + (size_t)(m0 + wave * 8 + ra) * KDIM + ca * 8;
  const bf16_t* bg = BT + (size_t)(n0 + wave * 8 + ra) * KDIM + ca * 8;
  const int aoff0 = (wave * 8) * 64;
  const int aoff1 = (wave * 8 + 32) * 64;
  const int boff0 = (wave * 8) * 64;
  const int boff1 = (wave * 8 + 32) * 64;
  const int boff2 = (wave * 8 + 64) * 64;
  const int boff3 = (wave * 8 + 96) * 64;

  const int wm = (wave >> 1) * 32;
  const int wn = (wave & 1) * 64;
  const int lr = lane & 15;
  const int lt = lane >> 4;

  auto STAGE = [&](int buf, int k0) {
    gload16(As + buf * ABUF + aoff0, ag + k0);
    gload16(As + buf * ABUF + aoff1, ag + 32 * KDIM + k0);
    gload16(Bs + buf * BBUF + boff0, bg + k0);
    gload16(Bs + buf * BBUF + boff1, bg + 32 * KDIM + k0);
    gload16(Bs + buf * BBUF + boff2, bg + 64 * KDIM + k0);
    gload16(Bs + buf * BBUF + boff3, bg + 96 * KDIM + k0);
  };

  // prologue: 2-deep prefetch
  STAGE(0, 0);
  STAGE(1, 64);

  f32x4 acc[2][4] = {};

  for (int t = 0; t < NT; ++t) {
    // certify tile t: 6 newest in-flight loads are tile t+1 — keep them flying
    if (t < NT - 1) asm volatile("s_waitcnt vmcnt(6)" ::: "memory");
    else            asm volatile("s_waitcnt vmcnt(0)" ::: "memory");
    __builtin_amdgcn_s_barrier();   // publish: ALL waves certified tile t;
                                    // also orders iter t-1 reads vs write below
    if (t + 2 < NT) STAGE((t + 2) % 3, (t + 2) * 64);

    const bf16_t* Ab = As + (t % 3) * ABUF;
    const bf16_t* Bb = Bs + (t % 3) * BBUF;
    #pragma unroll
    for (int ks = 0; ks < 2; ++ks) {
      const int c = ks * 4 + lt;
      bf16x8 af[2], bfr[4];
      #pragma unroll
      for (int i = 0; i < 2; ++i) {
        const int row = wm + i * 16 + lr;
        af[i] = *(const bf16x8*)&Ab[row * 64 + ((c ^ (row & 7)) * 8)];
      }
      #pragma unroll
      for (int j = 0; j < 4; ++j) {
        const int row = wn + j * 16 + lr;
        bfr[j] = *(const bf16x8*)&Bb[row * 64 + ((c ^ (row & 7)) * 8)];
      }
      #pragma unroll
      for (int i = 0; i < 2; ++i)
        #pragma unroll
        for (int j = 0; j < 4; ++j)
          acc[i][j] = __builtin_amdgcn_mfma_f32_16x16x32_bf16(af[i], bfr[j], acc[i][j], 0, 0, 0);
    }
  }

  // C/D layout: col = lane&15 (n), row = (lane>>4)*4 + reg (m)
  const int q4 = lt << 2;
  const int colb = n0 + wn;
  #pragma unroll
  for (int i = 0; i < 2; ++i) {
    #pragma unroll
    for (int r = 0; r < 4; ++r) {
      const int mm = m0 + wm + i * 16 + q4 + r;
      if (EPI == 0) {
        const int pp = mm % NPATCH;
        const float* pe = pos + (size_t)pp * DMODEL;
        bf16_t* orow = (bf16_t*)outp + (size_t)mm * DMODEL;
        #pragma unroll
        for (int j = 0; j < 4; ++j) {
          const int nn = colb + j * 16 + lr;
          orow[nn] = (bf16_t)(acc[i][j][r] + bias[nn] + pe[nn]);
        }
      } else {
        float* orow = (float*)outp + (size_t)mm * DMODEL;
        #pragma unroll
        for (int j = 0; j < 4; ++j) {
          const int nn = colb + j * 16 + lr;
          orow[nn] = acc[i][j][r] + bias[nn];
        }
      }
    }
  }
}

// ---------------------------------------------------------------------------
// manifold_v5: coords/K0 (MFMA) + embed/residual/LN (VALU), fused, in-place.
// 1 wave per 16 rows, grid = MROWS/16 = 1568.
// ---------------------------------------------------------------------------
__global__ __launch_bounds__(64) void manifold_v5(
    bf16_t* __restrict__ x, const bf16_t* __restrict__ Wcsg,
    const float* __restrict__ b_coord, const float* __restrict__ b_spinor,
    const float* __restrict__ We, const float* __restrict__ be,
    const float* __restrict__ gamma, const float* __restrict__ beta)
{
  __shared__ float cbuf[16][12];

  const int lane = threadIdx.x;
  const int lr   = lane & 15;
  const int lk   = (lane >> 4) << 3;
  const int q4   = (lane >> 4) << 2;
  const int m0w  = blockIdx.x * 16;

  float bbv[4];
  #pragma unroll
  for (int r = 0; r < 4; ++r) {
    if (q4 == 0)      bbv[r] = b_coord[r];
    else if (q4 == 4) bbv[r] = b_coord[4 + r];
    else if (q4 == 8) bbv[r] = b_spinor[r];
    else              bbv[r] = 0.f;
  }

  // ---- phase A: coords + K0 (MFMA, weights from L1) ----
  const bf16_t* xrow = x + (size_t)(m0w + lr) * DMODEL + lk;
  const bf16_t* wrow = Wcsg + lr * DMODEL + lk;
  f32x4 acc1 = {0.f, 0.f, 0.f, 0.f};
  #pragma unroll
  for (int ks = 0; ks < 16; ++ks) {
    const bf16x8 bf = *(const bf16x8*)(xrow + ks * 32);
    const bf16x8 wf = *(const bf16x8*)(wrow + ks * 32);
    acc1 = __builtin_amdgcn_mfma_f32_16x16x32_bf16(wf, bf, acc1, 0, 0, 0);
  }
  float sv[4];
  #pragma unroll
  for (int r = 0; r < 4; ++r) sv[r] = acc1[r] + bbv[r];

  if (q4 == 8) {
    cbuf[lr][8] = sv[0] * sv[0] + sv[1] * sv[1] + sv[2] * sv[2] + sv[3] * sv[3];
  } else if (q4 == 0 || q4 == 4) {
    f32x4 st = {sv[0], sv[1], sv[2], sv[3]};
    *(f32x4*)&cbuf[lr][q4] = st;
  }
  __syncthreads();

  // ---- phase B: embed + residual + LN (VALU, reg-staged weights) ----
  const int n0 = lane * 8;
  f32x4 wlo[8], whi[8];
  #pragma unroll
  for (int dc = 0; dc < 8; ++dc) {
    wlo[dc] = *(const f32x4*)&We[dc * DMODEL + n0];
    whi[dc] = *(const f32x4*)&We[dc * DMODEL + n0 + 4];
  }
  const f32x4 beL = *(const f32x4*)&be[n0];
  const f32x4 beH = *(const f32x4*)&be[n0 + 4];
  const f32x4 gL  = *(const f32x4*)&gamma[n0];
  const f32x4 gH  = *(const f32x4*)&gamma[n0 + 4];
  const f32x4 btL = *(const f32x4*)&beta[n0];
  const f32x4 btH = *(const f32x4*)&beta[n0 + 4];

  #pragma unroll 2
  for (int rr = 0; rr < 16; ++rr) {
    const size_t row = (size_t)m0w + rr;
    const bf16x8 xv = *(const bf16x8*)(x + row * DMODEL + n0);
    const f32x4 c0 = *(const f32x4*)&cbuf[rr][0];
    const f32x4 c1 = *(const f32x4*)&cbuf[rr][4];
    const float k0 = cbuf[rr][8];

    float v[8];
    float s1 = 0.f, s2 = 0.f;
    #pragma unroll
    for (int e = 0; e < 4; ++e) {
      float xm = beL[e];
      #pragma unroll
      for (int dc = 0; dc < 4; ++dc) xm += c0[dc] * wlo[dc][e];
      #pragma unroll
      for (int dc = 0; dc < 4; ++dc) xm += c1[dc] * wlo[4 + dc][e];
      const float vv = xm * k0 + (float)xv[e];
      v[e] = vv; s1 += vv; s2 += vv * vv;
    }
    #pragma unroll
    for (int e = 0; e < 4; ++e) {
      float xm = beH[e];
      #pragma unroll
      for (int dc = 0; dc < 4; ++dc) xm += c0[dc] * whi[dc][e];
      #pragma unroll
      for (int dc = 0; dc < 4; ++dc) xm += c1[dc] * whi[4 + dc][e];
      const float vv = xm * k0 + (float)xv[4 + e];
      v[4 + e] = vv; s1 += vv; s2 += vv * vv;
    }

    #pragma unroll
    for (int off = 1; off <= 32; off <<= 1) {
      s1 += __shfl_xor(s1, off, 64);
      s2 += __shfl_xor(s2, off, 64);
    }
    const float mu  = s1 * (1.f / 512.f);
    const float var = s2 * (1.f / 512.f) - mu * mu;
    const float rs  = rsqrtf(var + 1e-5f);

    bf16x8 o;
    #pragma unroll
    for (int e = 0; e < 4; ++e) {
      o[e]     = (bf16_t)((v[e]     - mu) * rs * gL[e] + btL[e]);
      o[4 + e] = (bf16_t)((v[4 + e] - mu) * rs * gH[e] + btH[e]);
    }
    *(bf16x8*)(x + row * DMODEL + n0) = o;
  }
}

// ---------------------------------------------------------------------------
extern "C" void kernel_launch(void* const* d_in, const int* in_sizes, int n_in,
                              void* d_out, int out_size, void* d_ws, size_t ws_size,
                              hipStream_t stream)
{
  const float* images    = (const float*)d_in[0];
  const float* W_patch   = (const float*)d_in[1];
  const float* b_patch   = (const float*)d_in[2];
  const float* pos_embed = (const float*)d_in[3];
  const float* W_coord   = (const float*)d_in[4];
  const float* b_coord   = (const float*)d_in[5];
  const float* W_spinor  = (const float*)d_in[6];
  const float* b_spinor  = (const float*)d_in[7];
  const float* W_embed   = (const float*)d_in[8];
  const float* b_embed   = (const float*)d_in[9];
  const float* ln_gamma  = (const float*)d_in[10];
  const float* ln_beta   = (const float*)d_in[11];
  const float* W_out     = (const float*)d_in[12];
  const float* b_out     = (const float*)d_in[13];
  float* out = (float*)d_out;

  const size_t SZ_APAT = (size_t)MROWS * PDIM * 2;     // 38,535,168
  const size_t SZ_X    = (size_t)MROWS * DMODEL * 2;   // 25,690,112
  const size_t SZ_WPT  = (size_t)DMODEL * PDIM * 2;    //    786,432
  const size_t SZ_WOT  = (size_t)DMODEL * DMODEL * 2;  //    524,288

  char* ws = (char*)d_ws;
  char* p  = ws;
  bf16_t* Apat = (bf16_t*)p;   p += SZ_APAT;
  bf16_t* x    = (bf16_t*)p;   p += SZ_X;
  bf16_t* WpT  = (bf16_t*)p;   p += SZ_WPT;
  bf16_t* WoT  = (bf16_t*)p;   p += SZ_WOT;
  bf16_t* Wcsg = (bf16_t*)p;

  hipLaunchKernelGGL(transpose_to_bf16, dim3(8, 12), dim3(64, 4), 0, stream,
                     W_patch, WpT, PDIM, DMODEL);
  hipLaunchKernelGGL(transpose_to_bf16, dim3(8, 8), dim3(64, 4), 0, stream,
                     W_out, WoT, DMODEL, DMODEL);
  hipLaunchKernelGGL(manifold_prep, dim3(32), dim3(256), 0, stream,
                     W_coord, W_spinor, Wcsg);

  hipLaunchKernelGGL(patchify_bf16, dim3(32 * 3 * 28), dim3(256), 0, stream,
                     images, Apat);
  hipLaunchKernelGGL((gemm_bf16<PDIM, 0>), dim3(1568), dim3(256), 0, stream,
                     Apat, WpT, b_patch, pos_embed, (void*)x);

  hipLaunchKernelGGL(manifold_v5, dim3(MROWS / 16), dim3(64), 0, stream,
                     x, Wcsg, b_coord, b_spinor, W_embed, b_embed, ln_gamma, ln_beta);

  hipLaunchKernelGGL((gemm_bf16<DMODEL, 1>), dim3(1568), dim3(256), 0, stream,
                     x, WoT, b_out, (const float*)nullptr, (void*)out);
}

// Round 12
// 114.152 us; speedup vs baseline: 1.0798x; 1.0377x over previous
//
#include <hip/hip_runtime.h>
#include <hip/hip_bf16.h>
#include <stdint.h>

// ============================================================================
// ImageManifoldHead on MI355X (gfx950) — round 12
//
// Pipeline:
//   prep:   W_patch -> WpT bf16 [512][768]; W_out -> WoT bf16 [512][512]
//           manifold_prep: Wcsg bf16[16][512]
//   patchify_bf16: images f32 -> Apat bf16 [25088][768]   (BW-bound pass)
//   gemm1:  Apat @ WpT^T + b_patch + pos -> x bf16   (v7: max-occupancy)
//   manifold_v5: coords/K0 (MFMA) + embed/LN (VALU), 1 wave/16 rows, in-place
//   gemm2:  x @ WoT^T + b_out -> out f32             (v7)
//
// gemm v7 — occupancy-max: BM=64, BN=64, BK=64, 4 waves (2x2, 32x32/wave),
//   16 KB LDS -> 8 blocks/CU (full 32-wave slot cap), grid 3136.
//   Simple 2-barrier loop (R5/R6/R7/R11 all proved intra-block pipelining
//   loses to TLP here; R8 proved blocks/CU is the lever that works).
//   Chunk-XOR swizzle both sides (bank conflicts = 0, verified R5+).
//   n-major wg order: consecutive wgs share the A-tile (L2-hot).
// ============================================================================

typedef __bf16 bf16_t;
typedef bf16_t bf16x8 __attribute__((ext_vector_type(8)));
typedef bf16_t bf16x4 __attribute__((ext_vector_type(4)));
typedef float  f32x4  __attribute__((ext_vector_type(4)));

#define IMG     448
#define PSZ     16
#define NHP     28
#define NPATCH  784
#define PDIM    768
#define DMODEL  512
#define MROWS   25088

__device__ __forceinline__ void gload16(void* lds, const void* g) {
  __builtin_amdgcn_global_load_lds(
      (__attribute__((address_space(1))) void*)(uintptr_t)g,
      (__attribute__((address_space(3))) void*)lds,
      16, 0, 0);
}

// ---------------------------------------------------------------------------
// prep: transpose f32 [K][N] -> bf16 [N][K]
// ---------------------------------------------------------------------------
__global__ __launch_bounds__(256) void transpose_to_bf16(
    const float* __restrict__ src, bf16_t* __restrict__ dst, int K, int N)
{
  __shared__ float t[64][65];
  const int tx = threadIdx.x;
  const int ty = threadIdx.y;
  const int bx = blockIdx.x * 64;
  const int by = blockIdx.y * 64;
  #pragma unroll
  for (int r = ty; r < 64; r += 4)
    t[r][tx] = src[(size_t)(by + r) * N + (bx + tx)];
  __syncthreads();
  #pragma unroll
  for (int r = ty; r < 64; r += 4)
    dst[(size_t)(bx + r) * K + (by + tx)] = (bf16_t)t[tx][r];
}

// ---------------------------------------------------------------------------
// manifold_prep: Wcsg [16][512]: r<8: Wc[n][r]; r 8-11: Ws[n][r-8]; else 0
// ---------------------------------------------------------------------------
__global__ __launch_bounds__(256) void manifold_prep(
    const float* __restrict__ Wc, const float* __restrict__ Ws,
    bf16_t* __restrict__ Wcsg)
{
  const int idx = blockIdx.x * 256 + threadIdx.x;   // grid 32 -> 8192
  if (idx < 8192) {
    const int r = idx >> 9, n = idx & 511;
    float v = 0.f;
    if (r < 8)       v = Wc[n * 8 + r];
    else if (r < 12) v = Ws[n * 4 + (r - 8)];
    Wcsg[idx] = (bf16_t)v;
  }
}

// ---------------------------------------------------------------------------
// patchify_bf16: images (B,3,448,448) f32 -> Apat [25088][768] bf16
// ---------------------------------------------------------------------------
__global__ __launch_bounds__(256) void patchify_bf16(
    const float* __restrict__ images, bf16_t* __restrict__ Apat)
{
  __shared__ bf16_t t[16][456];
  const int tid = threadIdx.x;
  const int bid = blockIdx.x;
  const int b = bid / 84, rem = bid % 84;
  const int c = rem / 28, ph = rem % 28;
  const float* src = images + ((size_t)(b * 3 + c) * IMG + ph * PSZ) * IMG;

  #pragma unroll
  for (int idx = tid; idx < 16 * 112; idx += 256) {
    const int i = idx / 112, x4 = idx % 112;
    const float4 v = *(const float4*)(src + (size_t)i * IMG + x4 * 4);
    bf16x4 w;
    w[0] = (bf16_t)v.x; w[1] = (bf16_t)v.y; w[2] = (bf16_t)v.z; w[3] = (bf16_t)v.w;
    *(bf16x4*)&t[i][x4 * 4] = w;
  }
  __syncthreads();

  const size_t mbase = (size_t)b * NPATCH + (size_t)ph * NHP;
  #pragma unroll
  for (int idx = tid; idx < 28 * 64; idx += 256) {
    const int pw = idx >> 6, e = idx & 63;
    const int i = e >> 2, j4 = e & 3;
    const bf16x4 w = *(const bf16x4*)&t[i][pw * 16 + j4 * 4];
    *(bf16x4*)&Apat[(mbase + pw) * PDIM + c * 256 + i * 16 + j4 * 4] = w;
  }
}

// ---------------------------------------------------------------------------
// gemm v7: C[M][512] = A[M][KDIM] @ BT[512][KDIM]^T
// BM=64, BN=64, BK=64; 4 waves (2x2), 32x32 output per wave; 16 KB LDS.
// grid = (M/64)*(512/64) = 3136 (1D), XCD swizzle (3136 = 8*392).
// n-major within wg: n0 = (wg&7)*64, m0 = (wg>>3)*64 -> consecutive wgs on
// one XCD share the A-tile (L2-hot).
// ---------------------------------------------------------------------------
template<int KDIM, int EPI>
__global__ __launch_bounds__(256) void gemm_bf16(
    const bf16_t* __restrict__ A, const bf16_t* __restrict__ BT,
    const float* __restrict__ bias, const float* __restrict__ pos,
    void* __restrict__ outp)
{
  __shared__ bf16_t As[64 * 64];    // 8 KB
  __shared__ bf16_t Bs[64 * 64];    // 8 KB
  constexpr int NT = KDIM / 64;

  const int tid  = threadIdx.x;
  const int orig = blockIdx.x;
  const int wg   = (orig & 7) * 392 + (orig >> 3);   // bijective, 3136=8*392
  const int n0   = (wg & 7) * 64;
  const int m0   = (wg >> 3) * 64;

  const int wave = tid >> 6, lane = tid & 63;

  // staging: lane -> (row ra 0..7, global chunk ca = (lane&7) ^ ra)
  const int ra = lane >> 3;
  const int ca = (lane & 7) ^ ra;
  const bf16_t* ag = A  + (size_t)(m0 + wave * 8 + ra) * KDIM + ca * 8;
  const bf16_t* bg = BT + (size_t)(n0 + wave * 8 + ra) * KDIM + ca * 8;
  bf16_t* al0 = As + (wave * 8) * 64;
  bf16_t* al1 = As + (wave * 8 + 32) * 64;
  bf16_t* bl0 = Bs + (wave * 8) * 64;
  bf16_t* bl1 = Bs + (wave * 8 + 32) * 64;

  const int wm = (wave >> 1) * 32;   // 0 / 32
  const int wn = (wave & 1) * 32;    // 0 / 32
  const int lr = lane & 15;
  const int lt = lane >> 4;          // 0..3

  f32x4 acc[2][2] = {};

  for (int t = 0; t < NT; ++t) {
    const int k0 = t * 64;
    __syncthreads();                 // prev step's LDS reads complete
    gload16(al0, ag + k0);
    gload16(al1, ag + 32 * KDIM + k0);
    gload16(bl0, bg + k0);
    gload16(bl1, bg + 32 * KDIM + k0);
    __syncthreads();                 // implies vmcnt(0): DMA landed

    #pragma unroll
    for (int ks = 0; ks < 2; ++ks) {
      const int c = ks * 4 + lt;     // nominal chunk 0..7
      bf16x8 af[2], bfr[2];
      #pragma unroll
      for (int i = 0; i < 2; ++i) {
        const int row = wm + i * 16 + lr;
        af[i] = *(const bf16x8*)&As[row * 64 + ((c ^ (row & 7)) * 8)];
      }
      #pragma unroll
      for (int j = 0; j < 2; ++j) {
        const int row = wn + j * 16 + lr;
        bfr[j] = *(const bf16x8*)&Bs[row * 64 + ((c ^ (row & 7)) * 8)];
      }
      #pragma unroll
      for (int i = 0; i < 2; ++i)
        #pragma unroll
        for (int j = 0; j < 2; ++j)
          acc[i][j] = __builtin_amdgcn_mfma_f32_16x16x32_bf16(af[i], bfr[j], acc[i][j], 0, 0, 0);
    }
  }

  // C/D layout: col = lane&15 (n), row = (lane>>4)*4 + reg (m)
  const int q4 = lt << 2;
  const int colb = n0 + wn;
  #pragma unroll
  for (int i = 0; i < 2; ++i) {
    #pragma unroll
    for (int r = 0; r < 4; ++r) {
      const int mm = m0 + wm + i * 16 + q4 + r;
      if (EPI == 0) {
        const int pp = mm % NPATCH;
        const float* pe = pos + (size_t)pp * DMODEL;
        bf16_t* orow = (bf16_t*)outp + (size_t)mm * DMODEL;
        #pragma unroll
        for (int j = 0; j < 2; ++j) {
          const int nn = colb + j * 16 + lr;
          orow[nn] = (bf16_t)(acc[i][j][r] + bias[nn] + pe[nn]);
        }
      } else {
        float* orow = (float*)outp + (size_t)mm * DMODEL;
        #pragma unroll
        for (int j = 0; j < 2; ++j) {
          const int nn = colb + j * 16 + lr;
          orow[nn] = acc[i][j][r] + bias[nn];
        }
      }
    }
  }
}

// ---------------------------------------------------------------------------
// manifold_v5: coords/K0 (MFMA) + embed/residual/LN (VALU), fused, in-place.
// 1 wave per 16 rows, grid = MROWS/16 = 1568.
// ---------------------------------------------------------------------------
__global__ __launch_bounds__(64) void manifold_v5(
    bf16_t* __restrict__ x, const bf16_t* __restrict__ Wcsg,
    const float* __restrict__ b_coord, const float* __restrict__ b_spinor,
    const float* __restrict__ We, const float* __restrict__ be,
    const float* __restrict__ gamma, const float* __restrict__ beta)
{
  __shared__ float cbuf[16][12];

  const int lane = threadIdx.x;
  const int lr   = lane & 15;
  const int lk   = (lane >> 4) << 3;
  const int q4   = (lane >> 4) << 2;
  const int m0w  = blockIdx.x * 16;

  float bbv[4];
  #pragma unroll
  for (int r = 0; r < 4; ++r) {
    if (q4 == 0)      bbv[r] = b_coord[r];
    else if (q4 == 4) bbv[r] = b_coord[4 + r];
    else if (q4 == 8) bbv[r] = b_spinor[r];
    else              bbv[r] = 0.f;
  }

  // ---- phase A: coords + K0 (MFMA, weights from L1) ----
  const bf16_t* xrow = x + (size_t)(m0w + lr) * DMODEL + lk;
  const bf16_t* wrow = Wcsg + lr * DMODEL + lk;
  f32x4 acc1 = {0.f, 0.f, 0.f, 0.f};
  #pragma unroll
  for (int ks = 0; ks < 16; ++ks) {
    const bf16x8 bf = *(const bf16x8*)(xrow + ks * 32);
    const bf16x8 wf = *(const bf16x8*)(wrow + ks * 32);
    acc1 = __builtin_amdgcn_mfma_f32_16x16x32_bf16(wf, bf, acc1, 0, 0, 0);
  }
  float sv[4];
  #pragma unroll
  for (int r = 0; r < 4; ++r) sv[r] = acc1[r] + bbv[r];

  if (q4 == 8) {
    cbuf[lr][8] = sv[0] * sv[0] + sv[1] * sv[1] + sv[2] * sv[2] + sv[3] * sv[3];
  } else if (q4 == 0 || q4 == 4) {
    f32x4 st = {sv[0], sv[1], sv[2], sv[3]};
    *(f32x4*)&cbuf[lr][q4] = st;
  }
  __syncthreads();

  // ---- phase B: embed + residual + LN (VALU, reg-staged weights) ----
  const int n0 = lane * 8;
  f32x4 wlo[8], whi[8];
  #pragma unroll
  for (int dc = 0; dc < 8; ++dc) {
    wlo[dc] = *(const f32x4*)&We[dc * DMODEL + n0];
    whi[dc] = *(const f32x4*)&We[dc * DMODEL + n0 + 4];
  }
  const f32x4 beL = *(const f32x4*)&be[n0];
  const f32x4 beH = *(const f32x4*)&be[n0 + 4];
  const f32x4 gL  = *(const f32x4*)&gamma[n0];
  const f32x4 gH  = *(const f32x4*)&gamma[n0 + 4];
  const f32x4 btL = *(const f32x4*)&beta[n0];
  const f32x4 btH = *(const f32x4*)&beta[n0 + 4];

  #pragma unroll 2
  for (int rr = 0; rr < 16; ++rr) {
    const size_t row = (size_t)m0w + rr;
    const bf16x8 xv = *(const bf16x8*)(x + row * DMODEL + n0);
    const f32x4 c0 = *(const f32x4*)&cbuf[rr][0];
    const f32x4 c1 = *(const f32x4*)&cbuf[rr][4];
    const float k0 = cbuf[rr][8];

    float v[8];
    float s1 = 0.f, s2 = 0.f;
    #pragma unroll
    for (int e = 0; e < 4; ++e) {
      float xm = beL[e];
      #pragma unroll
      for (int dc = 0; dc < 4; ++dc) xm += c0[dc] * wlo[dc][e];
      #pragma unroll
      for (int dc = 0; dc < 4; ++dc) xm += c1[dc] * wlo[4 + dc][e];
      const float vv = xm * k0 + (float)xv[e];
      v[e] = vv; s1 += vv; s2 += vv * vv;
    }
    #pragma unroll
    for (int e = 0; e < 4; ++e) {
      float xm = beH[e];
      #pragma unroll
      for (int dc = 0; dc < 4; ++dc) xm += c0[dc] * whi[dc][e];
      #pragma unroll
      for (int dc = 0; dc < 4; ++dc) xm += c1[dc] * whi[4 + dc][e];
      const float vv = xm * k0 + (float)xv[4 + e];
      v[4 + e] = vv; s1 += vv; s2 += vv * vv;
    }

    #pragma unroll
    for (int off = 1; off <= 32; off <<= 1) {
      s1 += __shfl_xor(s1, off, 64);
      s2 += __shfl_xor(s2, off, 64);
    }
    const float mu  = s1 * (1.f / 512.f);
    const float var = s2 * (1.f / 512.f) - mu * mu;
    const float rs  = rsqrtf(var + 1e-5f);

    bf16x8 o;
    #pragma unroll
    for (int e = 0; e < 4; ++e) {
      o[e]     = (bf16_t)((v[e]     - mu) * rs * gL[e] + btL[e]);
      o[4 + e] = (bf16_t)((v[4 + e] - mu) * rs * gH[e] + btH[e]);
    }
    *(bf16x8*)(x + row * DMODEL + n0) = o;
  }
}

// ---------------------------------------------------------------------------
extern "C" void kernel_launch(void* const* d_in, const int* in_sizes, int n_in,
                              void* d_out, int out_size, void* d_ws, size_t ws_size,
                              hipStream_t stream)
{
  const float* images    = (const float*)d_in[0];
  const float* W_patch   = (const float*)d_in[1];
  const float* b_patch   = (const float*)d_in[2];
  const float* pos_embed = (const float*)d_in[3];
  const float* W_coord   = (const float*)d_in[4];
  const float* b_coord   = (const float*)d_in[5];
  const float* W_spinor  = (const float*)d_in[6];
  const float* b_spinor  = (const float*)d_in[7];
  const float* W_embed   = (const float*)d_in[8];
  const float* b_embed   = (const float*)d_in[9];
  const float* ln_gamma  = (const float*)d_in[10];
  const float* ln_beta   = (const float*)d_in[11];
  const float* W_out     = (const float*)d_in[12];
  const float* b_out     = (const float*)d_in[13];
  float* out = (float*)d_out;

  const size_t SZ_APAT = (size_t)MROWS * PDIM * 2;     // 38,535,168
  const size_t SZ_X    = (size_t)MROWS * DMODEL * 2;   // 25,690,112
  const size_t SZ_WPT  = (size_t)DMODEL * PDIM * 2;    //    786,432
  const size_t SZ_WOT  = (size_t)DMODEL * DMODEL * 2;  //    524,288

  char* ws = (char*)d_ws;
  char* p  = ws;
  bf16_t* Apat = (bf16_t*)p;   p += SZ_APAT;
  bf16_t* x    = (bf16_t*)p;   p += SZ_X;
  bf16_t* WpT  = (bf16_t*)p;   p += SZ_WPT;
  bf16_t* WoT  = (bf16_t*)p;   p += SZ_WOT;
  bf16_t* Wcsg = (bf16_t*)p;

  hipLaunchKernelGGL(transpose_to_bf16, dim3(8, 12), dim3(64, 4), 0, stream,
                     W_patch, WpT, PDIM, DMODEL);
  hipLaunchKernelGGL(transpose_to_bf16, dim3(8, 8), dim3(64, 4), 0, stream,
                     W_out, WoT, DMODEL, DMODEL);
  hipLaunchKernelGGL(manifold_prep, dim3(32), dim3(256), 0, stream,
                     W_coord, W_spinor, Wcsg);

  hipLaunchKernelGGL(patchify_bf16, dim3(32 * 3 * 28), dim3(256), 0, stream,
                     images, Apat);
  hipLaunchKernelGGL((gemm_bf16<PDIM, 0>), dim3(3136), dim3(256), 0, stream,
                     Apat, WpT, b_patch, pos_embed, (void*)x);

  hipLaunchKernelGGL(manifold_v5, dim3(MROWS / 16), dim3(64), 0, stream,
                     x, Wcsg, b_coord, b_spinor, W_embed, b_embed, ln_gamma, ln_beta);

  hipLaunchKernelGGL((gemm_bf16<DMODEL, 1>), dim3(3136), dim3(256), 0, stream,
                     x, WoT, b_out, (const float*)nullptr, (void*)out);
}

// Round 13
// 108.208 us; speedup vs baseline: 1.1391x; 1.0549x over previous
//
#include <hip/hip_runtime.h>
#include <hip/hip_bf16.h>
#include <stdint.h>

// ============================================================================
// ImageManifoldHead on MI355X (gfx950) — round 13
//
// Pipeline (5 launches):
//   prep_all:  WpT bf16[512][768], WoT bf16[512][512], Wcsg bf16[16][512]
//   patchify_bf16: images f32 -> Apat bf16 [25088][768]
//   gemm1:  Apat @ WpT^T + b_patch + pos -> x bf16   (v5: BM64/BN128/BK64)
//   manifold_v6: coords/K0 (split-K MFMA) + embed/LN (VALU), 256-thr blocks,
//                12 waves/CU (R12's manifold_v5 was 6 waves/CU, ~25 us)
//   gemm2:  x @ WoT^T + b_out -> out f32             (v5)
// ============================================================================

typedef __bf16 bf16_t;
typedef bf16_t bf16x8 __attribute__((ext_vector_type(8)));
typedef bf16_t bf16x4 __attribute__((ext_vector_type(4)));
typedef float  f32x4  __attribute__((ext_vector_type(4)));

#define IMG     448
#define PSZ     16
#define NHP     28
#define NPATCH  784
#define PDIM    768
#define DMODEL  512
#define MROWS   25088

__device__ __forceinline__ void gload16(void* lds, const void* g) {
  __builtin_amdgcn_global_load_lds(
      (__attribute__((address_space(1))) void*)(uintptr_t)g,
      (__attribute__((address_space(3))) void*)lds,
      16, 0, 0);
}

// ---------------------------------------------------------------------------
// prep_all: blocks 0-95 WpT transpose tiles; 96-159 WoT; 160 Wcsg pack.
// ---------------------------------------------------------------------------
__global__ __launch_bounds__(256) void prep_all(
    const float* __restrict__ Wp, const float* __restrict__ Wo,
    const float* __restrict__ Wc, const float* __restrict__ Ws,
    bf16_t* __restrict__ WpT, bf16_t* __restrict__ WoT,
    bf16_t* __restrict__ Wcsg)
{
  __shared__ float t[64][65];
  const int tid = threadIdx.x;
  const int blk = blockIdx.x;

  if (blk >= 160) {
    for (int idx = tid; idx < 8192; idx += 256) {
      const int r = idx >> 9, n = idx & 511;
      float v = 0.f;
      if (r < 8)       v = Wc[n * 8 + r];
      else if (r < 12) v = Ws[n * 4 + (r - 8)];
      Wcsg[idx] = (bf16_t)v;
    }
    return;
  }

  const float* src;  bf16_t* dst;  int K, N, bx, by;
  if (blk < 96) { src = Wp; dst = WpT; K = PDIM;   N = DMODEL;
                  bx = (blk & 7) * 64;        by = (blk >> 3) * 64; }
  else          { src = Wo; dst = WoT; K = DMODEL; N = DMODEL;
                  bx = ((blk - 96) & 7) * 64; by = ((blk - 96) >> 3) * 64; }

  const int tx = tid & 63, ty = tid >> 6;
  #pragma unroll
  for (int r = ty; r < 64; r += 4)
    t[r][tx] = src[(size_t)(by + r) * N + (bx + tx)];
  __syncthreads();
  #pragma unroll
  for (int r = ty; r < 64; r += 4)
    dst[(size_t)(bx + r) * K + (by + tx)] = (bf16_t)t[tx][r];
}

// ---------------------------------------------------------------------------
// patchify_bf16: images (B,3,448,448) f32 -> Apat [25088][768] bf16
// ---------------------------------------------------------------------------
__global__ __launch_bounds__(256) void patchify_bf16(
    const float* __restrict__ images, bf16_t* __restrict__ Apat)
{
  __shared__ bf16_t t[16][456];
  const int tid = threadIdx.x;
  const int bid = blockIdx.x;
  const int b = bid / 84, rem = bid % 84;
  const int c = rem / 28, ph = rem % 28;
  const float* src = images + ((size_t)(b * 3 + c) * IMG + ph * PSZ) * IMG;

  #pragma unroll
  for (int idx = tid; idx < 16 * 112; idx += 256) {
    const int i = idx / 112, x4 = idx % 112;
    const float4 v = *(const float4*)(src + (size_t)i * IMG + x4 * 4);
    bf16x4 w;
    w[0] = (bf16_t)v.x; w[1] = (bf16_t)v.y; w[2] = (bf16_t)v.z; w[3] = (bf16_t)v.w;
    *(bf16x4*)&t[i][x4 * 4] = w;
  }
  __syncthreads();

  const size_t mbase = (size_t)b * NPATCH + (size_t)ph * NHP;
  #pragma unroll
  for (int idx = tid; idx < 28 * 64; idx += 256) {
    const int pw = idx >> 6, e = idx & 63;
    const int i = e >> 2, j4 = e & 3;
    const bf16x4 w = *(const bf16x4*)&t[i][pw * 16 + j4 * 4];
    *(bf16x4*)&Apat[(mbase + pw) * PDIM + c * 256 + i * 16 + j4 * 4] = w;
  }
}

// ---------------------------------------------------------------------------
// gemm v5 (R9 champion): C[M][512] = A[M][KDIM] @ BT[512][KDIM]^T
// BM=64, BN=128, BK=64, 4 waves, 24 KB LDS, grid 1568, XCD swizzle,
// chunk-XOR LDS swizzle both sides (bank conflicts = 0).
// ---------------------------------------------------------------------------
template<int KDIM, int EPI>
__global__ __launch_bounds__(256) void gemm_bf16(
    const bf16_t* __restrict__ A, const bf16_t* __restrict__ BT,
    const float* __restrict__ bias, const float* __restrict__ pos,
    void* __restrict__ outp)
{
  __shared__ bf16_t As[64 * 64];    //  8 KB
  __shared__ bf16_t Bs[128 * 64];   // 16 KB
  constexpr int NT = KDIM / 64;

  const int tid  = threadIdx.x;
  const int orig = blockIdx.x;
  const int wg   = (orig & 7) * 196 + (orig >> 3);   // bijective, 1568=8*196
  const int n0   = (wg & 3) * 128;
  const int m0   = (wg >> 2) * 64;

  const int wave = tid >> 6, lane = tid & 63;

  const int ra = lane >> 3;
  const int ca = (lane & 7) ^ ra;
  const bf16_t* ag = A  + (size_t)(m0 + wave * 8 + ra) * KDIM + ca * 8;
  const bf16_t* bg = BT + (size_t)(n0 + wave * 8 + ra) * KDIM + ca * 8;
  bf16_t* al0 = As + (wave * 8) * 64;
  bf16_t* al1 = As + (wave * 8 + 32) * 64;
  bf16_t* bl0 = Bs + (wave * 8) * 64;
  bf16_t* bl1 = Bs + (wave * 8 + 32) * 64;
  bf16_t* bl2 = Bs + (wave * 8 + 64) * 64;
  bf16_t* bl3 = Bs + (wave * 8 + 96) * 64;

  const int wm = (wave >> 1) * 32;
  const int wn = (wave & 1) * 64;
  const int lr = lane & 15;
  const int lt = lane >> 4;

  f32x4 acc[2][4] = {};

  for (int t = 0; t < NT; ++t) {
    const int k0 = t * 64;
    __syncthreads();
    gload16(al0, ag + k0);
    gload16(al1, ag + 32 * KDIM + k0);
    gload16(bl0, bg + k0);
    gload16(bl1, bg + 32 * KDIM + k0);
    gload16(bl2, bg + 64 * KDIM + k0);
    gload16(bl3, bg + 96 * KDIM + k0);
    __syncthreads();

    #pragma unroll
    for (int ks = 0; ks < 2; ++ks) {
      const int c = ks * 4 + lt;
      bf16x8 af[2], bfr[4];
      #pragma unroll
      for (int i = 0; i < 2; ++i) {
        const int row = wm + i * 16 + lr;
        af[i] = *(const bf16x8*)&As[row * 64 + ((c ^ (row & 7)) * 8)];
      }
      #pragma unroll
      for (int j = 0; j < 4; ++j) {
        const int row = wn + j * 16 + lr;
        bfr[j] = *(const bf16x8*)&Bs[row * 64 + ((c ^ (row & 7)) * 8)];
      }
      #pragma unroll
      for (int i = 0; i < 2; ++i)
        #pragma unroll
        for (int j = 0; j < 4; ++j)
          acc[i][j] = __builtin_amdgcn_mfma_f32_16x16x32_bf16(af[i], bfr[j], acc[i][j], 0, 0, 0);
    }
  }

  const int q4 = lt << 2;
  const int colb = n0 + wn;
  #pragma unroll
  for (int i = 0; i < 2; ++i) {
    #pragma unroll
    for (int r = 0; r < 4; ++r) {
      const int mm = m0 + wm + i * 16 + q4 + r;
      if (EPI == 0) {
        const int pp = mm % NPATCH;
        const float* pe = pos + (size_t)pp * DMODEL;
        bf16_t* orow = (bf16_t*)outp + (size_t)mm * DMODEL;
        #pragma unroll
        for (int j = 0; j < 4; ++j) {
          const int nn = colb + j * 16 + lr;
          orow[nn] = (bf16_t)(acc[i][j][r] + bias[nn] + pe[nn]);
        }
      } else {
        float* orow = (float*)outp + (size_t)mm * DMODEL;
        #pragma unroll
        for (int j = 0; j < 4; ++j) {
          const int nn = colb + j * 16 + lr;
          orow[nn] = acc[i][j][r] + bias[nn];
        }
      }
    }
  }
}

// ---------------------------------------------------------------------------
// manifold_v6: coords/K0 + embed/residual/LN fused, 256-thread blocks.
// grid = MROWS/32 = 784; 4 waves/block; 12 waves/CU.
// Phase A (split-K): wave (rg=w&1, kh=w>>1) computes the raw coords/spinor
//   partial for rows [blk*32+rg*16, +16) over k in [kh*256, +256) — 8 MFMAs.
//   Partials -> pbuf[kh][rg][row][comp] (no bias).
// Phase B: wave w owns local rows w*8..w*8+7; lane owns cols lane*8..+8.
//   c = p0+p1+b_coord; sp = p0+p1+b_spinor; K0 = sum sp^2 (squared AFTER sum).
//   embed on VALU w/ reg-staged f32 We/be/gamma/beta; residual; LN butterfly.
// ---------------------------------------------------------------------------
__global__ __launch_bounds__(256) void manifold_v6(
    bf16_t* __restrict__ x, const bf16_t* __restrict__ Wcsg,
    const float* __restrict__ b_coord, const float* __restrict__ b_spinor,
    const float* __restrict__ We, const float* __restrict__ be,
    const float* __restrict__ gamma, const float* __restrict__ beta)
{
  __shared__ float pbuf[2][2][16][12];   // [khalf][rowgrp][row][comp], 3 KB

  const int tid  = threadIdx.x;
  const int w    = tid >> 6;
  const int lane = tid & 63;
  const int rg   = w & 1;
  const int kh   = w >> 1;
  const int lr   = lane & 15;
  const int lk   = (lane >> 4) << 3;
  const int q4   = (lane >> 4) << 2;
  const size_t mbase = (size_t)blockIdx.x * 32;

  // ---- phase A: split-K coords/spinor partials (raw, no bias) ----
  const bf16_t* xrow = x + (mbase + rg * 16 + lr) * DMODEL + kh * 256 + lk;
  const bf16_t* wrow = Wcsg + lr * DMODEL + kh * 256 + lk;
  f32x4 acc1 = {0.f, 0.f, 0.f, 0.f};
  #pragma unroll
  for (int ks = 0; ks < 8; ++ks) {
    const bf16x8 bf = *(const bf16x8*)(xrow + ks * 32);
    const bf16x8 wf = *(const bf16x8*)(wrow + ks * 32);
    acc1 = __builtin_amdgcn_mfma_f32_16x16x32_bf16(wf, bf, acc1, 0, 0, 0);
  }
  if (q4 < 12) {
    #pragma unroll
    for (int r = 0; r < 4; ++r) pbuf[kh][rg][lr][q4 + r] = acc1[r];
  }
  __syncthreads();

  // ---- phase B: embed + residual + LN (8 rows per wave) ----
  const int n0 = lane * 8;
  f32x4 wlo[8], whi[8];
  #pragma unroll
  for (int dc = 0; dc < 8; ++dc) {
    wlo[dc] = *(const f32x4*)&We[dc * DMODEL + n0];
    whi[dc] = *(const f32x4*)&We[dc * DMODEL + n0 + 4];
  }
  const f32x4 beL = *(const f32x4*)&be[n0];
  const f32x4 beH = *(const f32x4*)&be[n0 + 4];
  const f32x4 gL  = *(const f32x4*)&gamma[n0];
  const f32x4 gH  = *(const f32x4*)&gamma[n0 + 4];
  const f32x4 btL = *(const f32x4*)&beta[n0];
  const f32x4 btH = *(const f32x4*)&beta[n0 + 4];
  float bc[8], bs[4];
  #pragma unroll
  for (int dc = 0; dc < 8; ++dc) bc[dc] = b_coord[dc];
  #pragma unroll
  for (int ds = 0; ds < 4; ++ds) bs[ds] = b_spinor[ds];

  #pragma unroll 2
  for (int rr = 0; rr < 8; ++rr) {
    const int rloc = w * 8 + rr;
    const int rg2  = rloc >> 4, r16 = rloc & 15;
    const float* p0 = &pbuf[0][rg2][r16][0];
    const float* p1 = &pbuf[1][rg2][r16][0];
    float c[8];
    #pragma unroll
    for (int dc = 0; dc < 8; ++dc) c[dc] = p0[dc] + p1[dc] + bc[dc];
    float k0 = 0.f;
    #pragma unroll
    for (int ds = 0; ds < 4; ++ds) {
      const float s = p0[8 + ds] + p1[8 + ds] + bs[ds];
      k0 += s * s;
    }

    const size_t row = mbase + rloc;
    const bf16x8 xv = *(const bf16x8*)(x + row * DMODEL + n0);

    float v[8];
    float s1 = 0.f, s2 = 0.f;
    #pragma unroll
    for (int e = 0; e < 4; ++e) {
      float xm = beL[e];
      #pragma unroll
      for (int dc = 0; dc < 8; ++dc) xm += c[dc] * wlo[dc][e];
      const float vv = xm * k0 + (float)xv[e];
      v[e] = vv; s1 += vv; s2 += vv * vv;
    }
    #pragma unroll
    for (int e = 0; e < 4; ++e) {
      float xm = beH[e];
      #pragma unroll
      for (int dc = 0; dc < 8; ++dc) xm += c[dc] * whi[dc][e];
      const float vv = xm * k0 + (float)xv[4 + e];
      v[4 + e] = vv; s1 += vv; s2 += vv * vv;
    }

    #pragma unroll
    for (int off = 1; off <= 32; off <<= 1) {
      s1 += __shfl_xor(s1, off, 64);
      s2 += __shfl_xor(s2, off, 64);
    }
    const float mu  = s1 * (1.f / 512.f);
    const float var = s2 * (1.f / 512.f) - mu * mu;
    const float rs  = rsqrtf(var + 1e-5f);

    bf16x8 o;
    #pragma unroll
    for (int e = 0; e < 4; ++e) {
      o[e]     = (bf16_t)((v[e]     - mu) * rs * gL[e] + btL[e]);
      o[4 + e] = (bf16_t)((v[4 + e] - mu) * rs * gH[e] + btH[e]);
    }
    *(bf16x8*)(x + row * DMODEL + n0) = o;
  }
}

// ---------------------------------------------------------------------------
extern "C" void kernel_launch(void* const* d_in, const int* in_sizes, int n_in,
                              void* d_out, int out_size, void* d_ws, size_t ws_size,
                              hipStream_t stream)
{
  const float* images    = (const float*)d_in[0];
  const float* W_patch   = (const float*)d_in[1];
  const float* b_patch   = (const float*)d_in[2];
  const float* pos_embed = (const float*)d_in[3];
  const float* W_coord   = (const float*)d_in[4];
  const float* b_coord   = (const float*)d_in[5];
  const float* W_spinor  = (const float*)d_in[6];
  const float* b_spinor  = (const float*)d_in[7];
  const float* W_embed   = (const float*)d_in[8];
  const float* b_embed   = (const float*)d_in[9];
  const float* ln_gamma  = (const float*)d_in[10];
  const float* ln_beta   = (const float*)d_in[11];
  const float* W_out     = (const float*)d_in[12];
  const float* b_out     = (const float*)d_in[13];
  float* out = (float*)d_out;

  const size_t SZ_APAT = (size_t)MROWS * PDIM * 2;     // 38,535,168
  const size_t SZ_X    = (size_t)MROWS * DMODEL * 2;   // 25,690,112
  const size_t SZ_WPT  = (size_t)DMODEL * PDIM * 2;    //    786,432
  const size_t SZ_WOT  = (size_t)DMODEL * DMODEL * 2;  //    524,288

  char* ws = (char*)d_ws;
  char* p  = ws;
  bf16_t* Apat = (bf16_t*)p;   p += SZ_APAT;
  bf16_t* x    = (bf16_t*)p;   p += SZ_X;
  bf16_t* WpT  = (bf16_t*)p;   p += SZ_WPT;
  bf16_t* WoT  = (bf16_t*)p;   p += SZ_WOT;
  bf16_t* Wcsg = (bf16_t*)p;

  hipLaunchKernelGGL(prep_all, dim3(161), dim3(256), 0, stream,
                     W_patch, W_out, W_coord, W_spinor, WpT, WoT, Wcsg);

  hipLaunchKernelGGL(patchify_bf16, dim3(32 * 3 * 28), dim3(256), 0, stream,
                     images, Apat);
  hipLaunchKernelGGL((gemm_bf16<PDIM, 0>), dim3(1568), dim3(256), 0, stream,
                     Apat, WpT, b_patch, pos_embed, (void*)x);

  hipLaunchKernelGGL(manifold_v6, dim3(MROWS / 32), dim3(256), 0, stream,
                     x, Wcsg, b_coord, b_spinor, W_embed, b_embed, ln_gamma, ln_beta);

  hipLaunchKernelGGL((gemm_bf16<DMODEL, 1>), dim3(1568), dim3(256), 0, stream,
                     x, WoT, b_out, (const float*)nullptr, (void*)out);
}